// Round 9
// baseline (528.070 us; speedup 1.0000x reference)
//
#include <hip/hip_runtime.h>

#define NPTS 30000
#define PSTR 30208      // padded point stride (118*256), safe overreach for MFMA tiles
#define BB 4
#define R2 4096
#define NIMG 12
#define NSORT 16        // 12 plane images + 4 query-bin images

typedef __attribute__((ext_vector_type(8))) short short8;
typedef __attribute__((ext_vector_type(4))) float floatx4;

__device__ __forceinline__ ushort f2bf(float x){
    union { float f; unsigned u; } v; v.f = x;
    unsigned r = (v.u + 0x7fffu + ((v.u >> 16) & 1u)) >> 16;   // RNE
    return (ushort)r;
}
__device__ __forceinline__ float bf2f(ushort u){
    union { unsigned u; float f; } v; v.u = ((unsigned)u) << 16; return v.f;
}
// channel slot permutation: slot = p64(ch); inverse orig = p64i(slot)
__device__ __forceinline__ int p64i(int k){ return (k & 3)*16 + (k >> 2); }

// ---- bin index, replicating reference fp32 op order ----
__device__ __forceinline__ int coord_bin(float v){
    float t = (v + 0.5f) / 1.100001f;
    t = fminf(fmaxf(t, 0.0f), 0.999999f);
    return (int)(t * 64.0f);
}

// async global->LDS, 16B per lane, dest = wave-uniform base + lane*16
__device__ __forceinline__ void gl_lds16(const ushort* g, ushort* l){
    __builtin_amdgcn_global_load_lds(
        (const __attribute__((address_space(1))) void*)g,
        (__attribute__((address_space(3))) void*)l, 16, 0, 0);
}

// ---- weight prep: permuted-k bf16 weights for MFMA GEMMs; also zeroes hist ----
__global__ void k_prep(const float* __restrict__ fc_pos_W, const float* __restrict__ fc_pos_b,
                       const float* __restrict__ blk0W, const float* __restrict__ blk1W,
                       const float* __restrict__ blkSW, const float* __restrict__ fccW,
                       const float* __restrict__ c1W, const float* __restrict__ c2W,
                       float* __restrict__ WposTp, float* __restrict__ bposP,
                       ushort* __restrict__ Wcat, ushort* __restrict__ W1p,
                       ushort* __restrict__ Wcp,
                       ushort* __restrict__ WB1, ushort* __restrict__ WB2,
                       int* __restrict__ hist){
    int t = blockIdx.x*256 + threadIdx.x;
    if (t < 384){ int d = t/128, s = t%128;
        int j = (s<64)? p64i(s) : 64 + p64i(s-64);
        WposTp[t] = fc_pos_W[j*3 + d]; return; }
    t -= 384;
    if (t < 128){ int j = (t<64)? p64i(t) : 64 + p64i(t-64);
        bposP[t] = fc_pos_b[j]; return; }
    t -= 128;
    if (t < 49152){ // Wcat[i][n 128][k' 128]: n<64 -> W0 row n, n>=64 -> Ws row n-64
        int i = t/16384, r = t%16384, n = r/128, kp = r%128;
        int ci = (kp<64)? p64i(kp) : 64 + p64i(kp-64);
        float v = (n<64)? blk0W[(i*64+n)*128 + ci] : blkSW[(i*64+(n-64))*128 + ci];
        Wcat[t] = f2bf(v); return; }
    t -= 49152;
    if (t < 12288){ // W1p[i][n 64][k' 64]
        int i = t/4096, r = t%4096, n = r/64, kp = r%64;
        W1p[t] = f2bf(blk1W[(i*64+n)*64 + p64i(kp)]); return; }
    t -= 12288;
    if (t < 16384){ // Wcp[n 256][k' 64]
        int n = t/64, kp = t%64;
        Wcp[t] = f2bf(fccW[n*64 + p64i(kp)]); return; }
    t -= 16384;
    if (t < 589824){ // WB1t [tap][cc][kc][q][ko 256][8e] -- coalesced conv b-loads; k' in G slot order
        int e = t & 7; int rest = t >> 3; int ko = rest & 255; int g5 = rest >> 8;
        int qq = g5 & 3; int kc = (g5 >> 2) & 1; int cc = (g5 >> 3) & 3; int tap = g5 >> 5;
        int kp = cc*64 + kc*32 + qq*8 + e;
        int ci = 64*(kp>>6) + p64i(kp & 63);
        WB1[t] = f2bf(c1W[(ko*256+ci)*9 + tap]); return; }
    t -= 589824;
    if (t < 589824){ // WB2t same layout, natural channels
        int e = t & 7; int rest = t >> 3; int ko = rest & 255; int g5 = rest >> 8;
        int qq = g5 & 3; int kc = (g5 >> 2) & 1; int cc = (g5 >> 3) & 3; int tap = g5 >> 5;
        int kp = cc*64 + kc*32 + qq*8 + e;
        WB2[t] = f2bf(c2W[(ko*256+kp)*9 + tap]); return; }
    t -= 589824;
    if (t < NSORT*R2){ hist[t] = 0; return; }   // replaces hipMemsetAsync
}

// ---- fc_pos + plane/query bins + hist atomics. NET0 bf16 [B][PSTR][128] slot order ----
__global__ void k_net0(const float* __restrict__ p, const float* __restrict__ query,
                       const float* __restrict__ WposTp, const float* __restrict__ bposP,
                       ushort* __restrict__ NET0, int* __restrict__ IDX,
                       int* __restrict__ hist){
    int pt = blockIdx.x*256 + threadIdx.x;
    int b = blockIdx.y;
    if (pt >= NPTS) return;
    const float* pp = p + ((long)b*NPTS + pt)*3;
    float p0 = pp[0], p1 = pp[1], p2 = pp[2];
    int c0 = coord_bin(p0), c1 = coord_bin(p1), c2 = coord_bin(p2);
    int i0 = c0 + 64*c2, i1 = c0 + 64*c1, i2 = c1 + 64*c2;
    IDX[(0*BB + b)*NPTS + pt] = i0;   // xz
    IDX[(1*BB + b)*NPTS + pt] = i1;   // xy
    IDX[(2*BB + b)*NPTS + pt] = i2;   // yz
    atomicAdd(&hist[(0*BB + b)*R2 + i0], 1);
    atomicAdd(&hist[(1*BB + b)*R2 + i1], 1);
    atomicAdd(&hist[(2*BB + b)*R2 + i2], 1);
    // query 3D coarse bin as sort-image 12+b
    const float* qp = query + ((long)b*NPTS + pt)*3;
    int qx = min((int)(fmaxf(qp[0], 0.0f)*16.0f), 15);
    int qy = min((int)(fmaxf(qp[1], 0.0f)*16.0f), 15);
    int qz = min((int)(fmaxf(qp[2], 0.0f)*16.0f), 15);
    int qi = (qx<<8) | (qy<<4) | qz;
    IDX[(12 + b)*NPTS + pt] = qi;
    atomicAdd(&hist[(12 + b)*R2 + qi], 1);
    ushort* out = NET0 + ((long)b*PSTR + pt)*128;
    #pragma unroll
    for (int s = 0; s < 128; s += 4){
        ushort4 v;
        v.x = f2bf(bposP[s+0] + p0*WposTp[s+0] + p1*WposTp[128+s+0] + p2*WposTp[256+s+0]);
        v.y = f2bf(bposP[s+1] + p0*WposTp[s+1] + p1*WposTp[128+s+1] + p2*WposTp[256+s+1]);
        v.z = f2bf(bposP[s+2] + p0*WposTp[s+2] + p1*WposTp[128+s+2] + p2*WposTp[256+s+2]);
        v.w = f2bf(bposP[s+3] + p0*WposTp[s+3] + p1*WposTp[128+s+3] + p2*WposTp[256+s+3]);
        *(ushort4*)(out + s) = v;
    }
}

__global__ void k_scan(const int* __restrict__ hist, int* __restrict__ binStart,
                       int* __restrict__ cursor){
    __shared__ int sums[256];
    int img = blockIdx.x; int tid = threadIdx.x;
    int v[16]; int s = 0;
    const int* h = hist + img*R2 + tid*16;
    #pragma unroll
    for (int i=0;i<16;i++){ v[i] = s; s += h[i]; }
    sums[tid] = s;
    __syncthreads();
    for (int d=1; d<256; d<<=1){
        int t = (tid>=d)? sums[tid-d] : 0;
        __syncthreads();
        sums[tid] += t;
        __syncthreads();
    }
    int base = (tid==0)? 0 : sums[tid-1];
    int* bs = binStart + img*R2 + tid*16;
    int* cu = cursor  + img*R2 + tid*16;
    #pragma unroll
    for (int i=0;i<16;i++){ bs[i] = base + v[i]; cu[i] = base + v[i]; }
}

__global__ void k_mklist(const int* __restrict__ IDX, int* __restrict__ cursor,
                         int* __restrict__ plist, int n){
    int t = blockIdx.x*256 + threadIdx.x;
    if (t >= n) return;
    int img = t / NPTS; int pt = t - img*NPTS;
    int bin = IDX[t];
    int pos = atomicAdd(&cursor[img*R2 + bin], 1);
    plist[img*NPTS + pos] = pt;
}

// ---- resblock on MFMA: wave=64 pts. GEMM1 [64x128]@[128->h64|sc64], LDS transpose,
//      GEMM2 relu(h)@W1 [64x64]; Y = sc + relu(dx), bf16 slot order.
//      POOLED: X2 half gathered from compact bin-mean table via idx_xz (L2-resident) ----
template<bool POOLED>
__global__ void __launch_bounds__(256) k_res_mfma(
        const ushort* __restrict__ X1, const ushort* __restrict__ X2, int s1, int s2,
        const int* __restrict__ idxp,
        const ushort* __restrict__ Wcat, const float* __restrict__ b0,
        const ushort* __restrict__ W1p, const float* __restrict__ b1,
        ushort* __restrict__ Y){
    __shared__ __align__(16) ushort lds[4][64*72];
    int tid = threadIdx.x, lane = tid & 63, w = tid >> 6;
    int m16 = lane & 15, q = lane >> 4;
    int b = blockIdx.y;
    int pt0 = blockIdx.x*256 + w*64;
    const ushort* x1 = X1 + (long)b*PSTR*s1;
    const ushort* x2 = POOLED ? (X2 + (long)b*R2*64) : (X2 + (long)b*PSTR*s2);
    int bi[4];
    if (POOLED){
        const int* ip = idxp + (long)b*NPTS;   // xz plane bins; padded pts read in-bounds garbage
        #pragma unroll
        for (int mt=0; mt<4; mt++) bi[mt] = ip[pt0 + mt*16 + m16];
    }
    floatx4 accH[4][4], accS[4][4];
    #pragma unroll
    for (int nt=0; nt<4; nt++){
        float bv = b0[nt*16 + m16];
        #pragma unroll
        for (int mt=0; mt<4; mt++){
            floatx4 t = {bv,bv,bv,bv}; accH[mt][nt] = t;
            floatx4 z = {0.f,0.f,0.f,0.f}; accS[mt][nt] = z;
        }
    }
    #pragma unroll
    for (int kk=0; kk<4; kk++){
        int off = (kk&1)*32 + q*8;
        short8 a[4], bh[4], bs[4];
        #pragma unroll
        for (int mt=0; mt<4; mt++){
            const ushort* ap;
            if (kk < 2)       ap = x1 + (long)(pt0 + mt*16 + m16)*s1 + off;
            else if (POOLED)  ap = x2 + (long)bi[mt]*64 + off;
            else              ap = x2 + (long)(pt0 + mt*16 + m16)*s2 + off;
            a[mt] = *(const short8*)ap;
        }
        #pragma unroll
        for (int nt=0; nt<4; nt++){
            bh[nt] = *(const short8*)(Wcat + (nt*16 + m16)*128 + kk*32 + q*8);
            bs[nt] = *(const short8*)(Wcat + ((nt+4)*16 + m16)*128 + kk*32 + q*8);
        }
        #pragma unroll
        for (int mt=0; mt<4; mt++)
            #pragma unroll
            for (int nt=0; nt<4; nt++){
                accH[mt][nt] = __builtin_amdgcn_mfma_f32_16x16x32_bf16(a[mt], bh[nt], accH[mt][nt], 0,0,0);
                accS[mt][nt] = __builtin_amdgcn_mfma_f32_16x16x32_bf16(a[mt], bs[nt], accS[mt][nt], 0,0,0);
            }
    }
    // relu(h) -> LDS in slot order (slot = m16*4 + nt, packed ushort4)
    ushort* myl = lds[w];
    #pragma unroll
    for (int mt=0; mt<4; mt++)
        #pragma unroll
        for (int r=0; r<4; r++){
            int ptl = mt*16 + q*4 + r;
            ushort4 hv;
            hv.x = f2bf(fmaxf(accH[mt][0][r], 0.0f));
            hv.y = f2bf(fmaxf(accH[mt][1][r], 0.0f));
            hv.z = f2bf(fmaxf(accH[mt][2][r], 0.0f));
            hv.w = f2bf(fmaxf(accH[mt][3][r], 0.0f));
            *(ushort4*)&myl[ptl*72 + m16*4] = hv;
        }
    // GEMM2: dx = relu(h) @ W1^T
    floatx4 accD[4][4];
    #pragma unroll
    for (int nt=0; nt<4; nt++){
        float bv = b1[nt*16 + m16];
        #pragma unroll
        for (int mt=0; mt<4; mt++){ floatx4 t = {bv,bv,bv,bv}; accD[mt][nt] = t; }
    }
    #pragma unroll
    for (int kk=0; kk<2; kk++){
        short8 a[4], bb[4];
        #pragma unroll
        for (int mt=0; mt<4; mt++)
            a[mt] = *(const short8*)&myl[(mt*16 + m16)*72 + kk*32 + q*8];
        #pragma unroll
        for (int nt=0; nt<4; nt++)
            bb[nt] = *(const short8*)(W1p + (nt*16 + m16)*64 + kk*32 + q*8);
        #pragma unroll
        for (int mt=0; mt<4; mt++)
            #pragma unroll
            for (int nt=0; nt<4; nt++)
                accD[mt][nt] = __builtin_amdgcn_mfma_f32_16x16x32_bf16(a[mt], bb[nt], accD[mt][nt], 0,0,0);
    }
    // Y = sc + relu(dx), slot-packed stores
    #pragma unroll
    for (int mt=0; mt<4; mt++)
        #pragma unroll
        for (int r=0; r<4; r++){
            int pt = pt0 + mt*16 + q*4 + r;
            if (pt < NPTS){
                ushort4 yv;
                yv.x = f2bf(accS[mt][0][r] + fmaxf(accD[mt][0][r], 0.0f));
                yv.y = f2bf(accS[mt][1][r] + fmaxf(accD[mt][1][r], 0.0f));
                yv.z = f2bf(accS[mt][2][r] + fmaxf(accD[mt][2][r], 0.0f));
                yv.w = f2bf(accS[mt][3][r] + fmaxf(accD[mt][3][r], 0.0f));
                *(ushort4*)(Y + ((long)b*PSTR + pt)*64 + m16*4) = yv;
            }
        }
}

// ---- xz pooling: bin means into compact table BINP[b][bin][64] (2 MB, L2-resident) ----
__global__ void k_binmean(const ushort* __restrict__ Y, const int* __restrict__ plist,
                          const int* __restrict__ binStart, const int* __restrict__ hist,
                          ushort* __restrict__ BINP){
    int tid = threadIdx.x; int lane = tid & 63; int wv = tid >> 6;
    int g = blockIdx.x*4 + wv;          // [0, 4*4096)
    int b = g >> 12; int bl = g & 4095;
    int idx = b*R2 + bl;
    int start = binStart[idx]; int cnt = hist[idx];
    const int* pl = plist + b*NPTS;
    const ushort* Yb = Y + (long)b*PSTR*64 + lane;
    float s = 0.0f;
    for (int i=0;i<cnt;i++){
        int pt = pl[start+i];
        s += bf2f(Yb[(long)pt*64]);
    }
    BINP[(long)idx*64 + lane] = f2bf(s / fmaxf((float)cnt, 1.0f));
}

// ---- fused plane bin-mean + fc_c: each block gathers its 64 bins' net-means into
//      LDS (row stride 72, conflict-free — proven k_res_mfma GEMM2 layout), then
//      GEMM [64 x 64] @ [64 -> 256] + bias; empty bins -> 0. Replaces k_gather64 +
//      global BIN64 round-trip (12 MB). Output keeps C/G slot order. ----
__global__ void __launch_bounds__(256) k_fc_bins(const ushort* __restrict__ Y,
        const int* __restrict__ plist, const int* __restrict__ binStart,
        const int* __restrict__ hist,
        const ushort* __restrict__ Wcp, const float* __restrict__ bc,
        ushort* __restrict__ G){
    __shared__ __align__(16) ushort lds[64*72];
    int tid = threadIdx.x, lane = tid & 63, wv = tid >> 6;
    int m16 = lane & 15, q = lane >> 4;
    int r0 = blockIdx.x*64;             // bin row base (row = img*4096 + bl)
    // phase 1: 4 waves x 16 bins -> bin means into LDS (lane = channel slot)
    for (int t = 0; t < 16; ++t){
        int lb = wv*16 + t;
        int row = r0 + lb;
        int img = row >> 12; int b = img & 3;
        int start = binStart[row]; int cnt = hist[row];
        const int* pl = plist + img*NPTS;
        const ushort* Yb = Y + (long)b*PSTR*64 + lane;
        float s = 0.0f;
        for (int i=0;i<cnt;i++) s += bf2f(Yb[(long)pl[start+i]*64]);
        lds[lb*72 + lane] = f2bf(s / fmaxf((float)cnt, 1.0f));
    }
    __syncthreads();
    // phase 2: GEMM from LDS
    int n0 = wv*64;
    floatx4 acc[4][4];
    #pragma unroll
    for (int nt=0; nt<4; nt++){
        float bv = bc[n0 + nt*16 + m16];
        #pragma unroll
        for (int mt=0; mt<4; mt++){ floatx4 t = {bv,bv,bv,bv}; acc[mt][nt] = t; }
    }
    #pragma unroll
    for (int kk=0; kk<2; kk++){
        short8 a[4], bb[4];
        #pragma unroll
        for (int mt=0; mt<4; mt++)
            a[mt] = *(const short8*)&lds[(mt*16 + m16)*72 + kk*32 + q*8];
        #pragma unroll
        for (int nt=0; nt<4; nt++)
            bb[nt] = *(const short8*)(Wcp + (n0 + nt*16 + m16)*64 + kk*32 + q*8);
        #pragma unroll
        for (int mt=0; mt<4; mt++)
            #pragma unroll
            for (int nt=0; nt<4; nt++)
                acc[mt][nt] = __builtin_amdgcn_mfma_f32_16x16x32_bf16(a[mt], bb[nt], acc[mt][nt], 0,0,0);
    }
    #pragma unroll
    for (int mt=0; mt<4; mt++)
        #pragma unroll
        for (int r=0; r<4; r++){
            int row = r0 + mt*16 + q*4 + r;
            int cnt = hist[row];
            ushort4 v;
            if (cnt > 0){
                v.x = f2bf(acc[mt][0][r]); v.y = f2bf(acc[mt][1][r]);
                v.z = f2bf(acc[mt][2][r]); v.w = f2bf(acc[mt][3][r]);
            } else {
                v.x = 0; v.y = 0; v.z = 0; v.w = 0;   // ref: empty bin -> 0, not bias
            }
            *(ushort4*)(G + (long)row*256 + n0 + m16*4) = v;
        }
}

// ---- conv 3x3 SAME + relu, 9-tap implicit GEMM on MFMA (r6 GOLDEN — do not touch) ----
// 1 output row x 256 out-ch per block; LDS 49.5KB -> exactly 3 blocks/CU, grid 768
// co-resident (r5 lesson: co-residency beats per-block B-traffic halving; the
// 4-row x 64-ko variant was abandoned after r7 swizzle bug + r8 replay race).
// A: LDS dbuf per 64-ch chunk via global_load_lds; 16B slots XOR-swizzled by (colh&7)
//    with inverse swizzle on the global source; halo cols 0/65 pre-zeroed.
// B: WBt[tap][cc][kc][q][ko][8] -> contiguous coalesced loads.
__global__ void __launch_bounds__(256, 3) k_conv_mfma(const ushort* __restrict__ IN,
        const ushort* __restrict__ WBt, const float* __restrict__ bias, ushort* __restrict__ OUT){
    __shared__ __align__(16) ushort lds[2][3*66*64];
    int tid = threadIdx.x;
    int lane = tid & 63;
    int w = tid >> 6;
    int n0 = __builtin_amdgcn_readfirstlane(w * 64);
    // bijective XCD-aware swizzle: 768 workgroups = 8 XCDs x 96 consecutive
    int bid = blockIdx.x;
    int wg = (bid & 7) * 96 + (bid >> 3);
    int img = wg >> 6;
    int y = wg & 63;
    const ushort* inb = IN + (long)img*4096*256;
    int m16 = lane & 15, q = lane >> 4;

    // zero halo cells (colh 0 and 65) in both buffers, once: 12 cells x 8 slots
    if (tid < 96){
        int st = tid & 7; int c = tid >> 3;
        int buf = c / 6; int rr = (c % 6) >> 1; int colh = (c & 1) * 65;
        short8 z = {0,0,0,0,0,0,0,0};
        *(short8*)&lds[buf][(rr*66 + colh)*64 + st*8] = z;
    }

    floatx4 acc[4][4];
    #pragma unroll
    for (int j=0;j<4;j++){
        float bv = bias[n0 + 16*j + m16];
        #pragma unroll
        for (int i=0;i<4;i++){ floatx4 t = {bv,bv,bv,bv}; acc[i][j] = t; }
    }

    // staging lane constants: cell-in-group, slot, swizzled source channel-group
    int sgx = lane >> 3;                 // 0..7 cells per wave-load
    int sst = lane & 7;                  // LDS slot this lane fills
    int sg  = sst ^ ((1 + sgx) & 7);     // global channel-group to fetch (inverse swizzle)

    auto stage = [&](int buf, int cc){
        #pragma unroll
        for (int r3 = 0; r3 < 3; ++r3){
            int gy = y + r3 - 1;
            if (gy < 0 || gy > 63) continue;           // block-uniform
            const ushort* grow = inb + (long)gy*64*256 + cc*64 + sg*8;
            #pragma unroll
            for (int t = 0; t < 2; ++t){
                int col8 = w + t*4;
                const ushort* gp = grow + (long)(col8*8 + sgx)*256;
                ushort* lp = &lds[buf][(r3*66 + 1 + col8*8)*64];
                gl_lds16(gp, lp);
            }
        }
    };

    auto compute = [&](int buf, int cc){
        const ushort* lb = &lds[buf][0];
        #pragma unroll
        for (int r3 = 0; r3 < 3; ++r3){
            int gy = y + r3 - 1;
            if (gy < 0 || gy > 63) continue;           // block-uniform
            #pragma unroll
            for (int s = 0; s < 3; ++s){
                int tap = r3*3 + s;
                #pragma unroll
                for (int kc = 0; kc < 2; ++kc){
                    short8 a[4], b[4];
                    #pragma unroll
                    for (int j=0;j<4;j++)
                        b[j] = *(const short8*)(WBt + (long)(tap*32 + cc*8 + kc*4 + q)*2048
                                                    + (n0 + 16*j + m16)*8);
                    #pragma unroll
                    for (int i=0;i<4;i++){
                        int colh = 16*i + m16 + s;
                        int sl = (kc*4 + q) ^ (colh & 7);
                        a[i] = *(const short8*)(lb + (r3*66 + colh)*64 + sl*8);
                    }
                    #pragma unroll
                    for (int i=0;i<4;i++)
                        #pragma unroll
                        for (int j=0;j<4;j++)
                            acc[i][j] = __builtin_amdgcn_mfma_f32_16x16x32_bf16(a[i], b[j], acc[i][j], 0, 0, 0);
                }
            }
        }
    };

    stage(0, 0);
    __syncthreads();           // halo zeros + chunk 0 staged
    #pragma unroll 1
    for (int cc = 0; cc < 4; ++cc){
        if (cc < 3) stage((cc+1)&1, cc+1);   // async prefetch; hides under b-load waits
        compute(cc&1, cc);
        __syncthreads();                      // next chunk staged + buf free to overwrite
    }

    long base = ((long)img*4096 + (long)y*64);
    #pragma unroll
    for (int i=0;i<4;i++){
        #pragma unroll
        for (int rr=0;rr<4;rr++){
            int px = 16*i + q*4 + rr;
            long rowoff = (base + px)*256;
            #pragma unroll
            for (int j=0;j<4;j++){
                float v = fmaxf(acc[i][j][rr], 0.0f);
                OUT[rowoff + n0 + 16*j + m16] = f2bf(v);
            }
        }
    }
}

// ---- bilinear sample (border, align_corners=False), sum 3 planes; sorted queries ----
__global__ void k_sample(const ushort* __restrict__ A2, const float* __restrict__ query,
                         const int* __restrict__ qlist, float* __restrict__ out){
    int lane = threadIdx.x & 63;
    int g = blockIdx.x*4 + (threadIdx.x >> 6);
    int b = blockIdx.y;
    int q = qlist[b*NPTS + g];
    const float* qp = query + ((long)b*NPTS + q)*3;
    float q0 = qp[0], q1 = qp[1], q2 = qp[2];
    float a0 = 0.f, a1 = 0.f, a2v = 0.f, a3 = 0.f;
    #pragma unroll
    for (int pl = 0; pl < 3; pl++){
        float qa = (pl==2) ? q1 : q0;
        float qb = (pl==1) ? q1 : q2;
        float gx = qa*2.0f - 1.0f, gy = qb*2.0f - 1.0f;
        float xf = ((gx + 1.0f)*64.0f - 1.0f)*0.5f;
        float yf = ((gy + 1.0f)*64.0f - 1.0f)*0.5f;
        xf = fminf(fmaxf(xf, 0.0f), 63.0f);
        yf = fminf(fmaxf(yf, 0.0f), 63.0f);
        float x0f = floorf(xf), y0f = floorf(yf);
        float wx = xf - x0f, wy = yf - y0f;
        int x0 = (int)x0f, y0 = (int)y0f;
        int x1 = min(x0+1, 63), y1 = min(y0+1, 63);
        const ushort* base = A2 + ((long)(pl*BB+b)*R2)*256 + lane*4;
        ushort4 t00 = *(const ushort4*)(base + (long)(y0*64+x0)*256);
        ushort4 t01 = *(const ushort4*)(base + (long)(y0*64+x1)*256);
        ushort4 t10 = *(const ushort4*)(base + (long)(y1*64+x0)*256);
        ushort4 t11 = *(const ushort4*)(base + (long)(y1*64+x1)*256);
        float w00 = (1.0f-wx)*(1.0f-wy), w01 = wx*(1.0f-wy);
        float w10 = (1.0f-wx)*wy,        w11 = wx*wy;
        a0  += bf2f(t00.x)*w00 + bf2f(t01.x)*w01 + bf2f(t10.x)*w10 + bf2f(t11.x)*w11;
        a1  += bf2f(t00.y)*w00 + bf2f(t01.y)*w01 + bf2f(t10.y)*w10 + bf2f(t11.y)*w11;
        a2v += bf2f(t00.z)*w00 + bf2f(t01.z)*w01 + bf2f(t10.z)*w10 + bf2f(t11.z)*w11;
        a3  += bf2f(t00.w)*w00 + bf2f(t01.w)*w01 + bf2f(t10.w)*w10 + bf2f(t11.w)*w11;
    }
    float4 r; r.x = a0; r.y = a1; r.z = a2v; r.w = a3;
    *(float4*)(out + ((long)b*NPTS + q)*256 + lane*4) = r;
}

extern "C" void kernel_launch(void* const* d_in, const int* in_sizes, int n_in,
                              void* d_out, int out_size, void* d_ws, size_t ws_size,
                              hipStream_t stream){
    (void)in_sizes; (void)n_in; (void)out_size; (void)ws_size;
    const float* p        = (const float*)d_in[0];
    const float* query    = (const float*)d_in[1];
    const float* fc_pos_W = (const float*)d_in[2];
    const float* fc_pos_b = (const float*)d_in[3];
    const float* blk0W    = (const float*)d_in[4];
    const float* blk0b    = (const float*)d_in[5];
    const float* blk1W    = (const float*)d_in[6];
    const float* blk1b    = (const float*)d_in[7];
    const float* blkSW    = (const float*)d_in[8];
    const float* fccW     = (const float*)d_in[9];
    const float* fccB     = (const float*)d_in[10];
    const float* c1W      = (const float*)d_in[11];
    const float* c1b      = (const float*)d_in[12];
    const float* c2W      = (const float*)d_in[13];
    const float* c2b      = (const float*)d_in[14];

    char* ws = (char*)d_ws;
    size_t off = 0;
    auto alloc = [&](size_t bytes)->char*{
        char* r = ws + off; off = (off + bytes + 255) & ~(size_t)255; return r; };
    float* WposTp = (float*)alloc(384*4);
    float* bposP  = (float*)alloc(128*4);
    ushort* Wcat  = (ushort*)alloc(49152UL*2);
    ushort* W1p   = (ushort*)alloc(12288UL*2);
    ushort* Wcp   = (ushort*)alloc(16384UL*2);
    ushort* WB1   = (ushort*)alloc(589824UL*2);
    ushort* WB2   = (ushort*)alloc(589824UL*2);
    int*   IDX   = (int*)  alloc((size_t)NSORT*NPTS*4);   // 12 plane imgs + 4 query imgs
    int*   hist  = (int*)  alloc((size_t)NSORT*R2*4);
    int*   binStart = (int*)alloc((size_t)NSORT*R2*4);
    int*   cursor   = (int*)alloc((size_t)NSORT*R2*4);
    int*   plist    = (int*)alloc((size_t)NSORT*NPTS*4);
    ushort* NET0 = (ushort*)alloc((size_t)BB*PSTR*128*2);
    ushort* Ya   = (ushort*)alloc((size_t)BB*PSTR*64*2);
    ushort* Yb   = (ushort*)alloc((size_t)BB*PSTR*64*2);
    ushort* BINP = (ushort*)alloc((size_t)BB*R2*64*2);    // compact xz pooling table (2 MB)
    ushort* G    = (ushort*)alloc(12582912UL*2);
    ushort* A1   = (ushort*)alloc(12582912UL*2);
    ushort* A2   = (ushort*)alloc(12582912UL*2);

    dim3 blk(256);
    // k_prep also zeroes hist (range appended past the weight ranges)
    k_prep<<<5170, blk, 0, stream>>>(fc_pos_W, fc_pos_b, blk0W, blk1W, blkSW, fccW, c1W, c2W,
                                     WposTp, bposP, Wcat, W1p, Wcp, WB1, WB2, hist);
    // net0 computes IDX + hist atomics (k_hist fused)
    k_net0<<<dim3(118, BB), blk, 0, stream>>>(p, query, WposTp, bposP, NET0, IDX, hist);
    k_scan  <<<NSORT, blk, 0, stream>>>(hist, binStart, cursor);
    k_mklist<<<(NSORT*NPTS + 255)/256, blk, 0, stream>>>(IDX, cursor, plist, NSORT*NPTS);
    // resblock 0: X1 = NET0 slots [0,64), X2 = NET0 slots [64,128)
    k_res_mfma<false><<<dim3(118,BB), blk, 0, stream>>>(NET0, NET0 + 64, 128, 128, nullptr,
                                                 Wcat, blk0b, W1p, blk1b, Ya);
    k_binmean<<<4096, blk, 0, stream>>>(Ya, plist, binStart, hist, BINP);
    k_res_mfma<true><<<dim3(118,BB), blk, 0, stream>>>(Ya, BINP, 64, 64, IDX,
                                                 Wcat + 16384, blk0b + 64, W1p + 4096, blk1b + 64, Yb);
    k_binmean<<<4096, blk, 0, stream>>>(Yb, plist, binStart, hist, BINP);
    k_res_mfma<true><<<dim3(118,BB), blk, 0, stream>>>(Yb, BINP, 64, 64, IDX,
                                                 Wcat + 32768, blk0b + 128, W1p + 8192, blk1b + 128, Ya);
    // fused bin-mean + fc_c: 768 blocks x 64 bins -> G (replaces k_gather64 + BIN64)
    k_fc_bins<<<768, blk, 0, stream>>>(Ya, plist, binStart, hist, Wcp, fccB, G);
    // convs on MFMA: r6 golden structure (1 row x 256 ch, 3 blocks/CU co-resident)
    k_conv_mfma<<<dim3(768), blk, 0, stream>>>(G,  WB1, c1b, A1);
    k_conv_mfma<<<dim3(768), blk, 0, stream>>>(A1, WB2, c2b, A2);
    // bilinear sample + plane sum, spatially-sorted query order (query sort = imgs 12..15)
    k_sample<<<dim3(7500,BB), blk, 0, stream>>>(A2, query, plist + 12*NPTS, (float*)d_out);
}

// Round 10
// 452.453 us; speedup vs baseline: 1.1671x; 1.1671x over previous
//
#include <hip/hip_runtime.h>

#define NPTS 30000
#define PSTR 30208      // padded point stride (118*256), safe overreach for MFMA tiles
#define BB 4
#define R2 4096
#define NIMG 12
#define NSORT 16        // 12 plane images + 4 query-bin images

typedef __attribute__((ext_vector_type(8))) short short8;
typedef __attribute__((ext_vector_type(4))) float floatx4;

__device__ __forceinline__ ushort f2bf(float x){
    union { float f; unsigned u; } v; v.f = x;
    unsigned r = (v.u + 0x7fffu + ((v.u >> 16) & 1u)) >> 16;   // RNE
    return (ushort)r;
}
__device__ __forceinline__ float bf2f(ushort u){
    union { unsigned u; float f; } v; v.u = ((unsigned)u) << 16; return v.f;
}
// channel slot permutation: slot = p64(ch); inverse orig = p64i(slot)
__device__ __forceinline__ int p64i(int k){ return (k & 3)*16 + (k >> 2); }

// ---- bin index, replicating reference fp32 op order ----
__device__ __forceinline__ int coord_bin(float v){
    float t = (v + 0.5f) / 1.100001f;
    t = fminf(fmaxf(t, 0.0f), 0.999999f);
    return (int)(t * 64.0f);
}

// async global->LDS, 16B per lane, dest = wave-uniform base + lane*16
__device__ __forceinline__ void gl_lds16(const ushort* g, ushort* l){
    __builtin_amdgcn_global_load_lds(
        (const __attribute__((address_space(1))) void*)g,
        (__attribute__((address_space(3))) void*)l, 16, 0, 0);
}

// ---- 4-unrolled bin gather: 4 independent row-load chains in flight (latency fix) ----
__device__ __forceinline__ float bin_gather_sum(const ushort* __restrict__ Yb,
                                                const int* __restrict__ pl,
                                                int start, int cnt){
    float s = 0.0f;
    int i = 0;
    for (; i + 4 <= cnt; i += 4){
        int p0 = pl[start+i+0], p1 = pl[start+i+1];
        int p2 = pl[start+i+2], p3 = pl[start+i+3];
        float v0 = bf2f(Yb[(long)p0*64]);
        float v1 = bf2f(Yb[(long)p1*64]);
        float v2 = bf2f(Yb[(long)p2*64]);
        float v3 = bf2f(Yb[(long)p3*64]);
        s += ((v0 + v1) + v2) + v3;
    }
    for (; i < cnt; ++i) s += bf2f(Yb[(long)pl[start+i]*64]);
    return s;
}

// ---- weight prep: permuted-k bf16 weights for MFMA GEMMs; also zeroes hist ----
__global__ void k_prep(const float* __restrict__ fc_pos_W, const float* __restrict__ fc_pos_b,
                       const float* __restrict__ blk0W, const float* __restrict__ blk1W,
                       const float* __restrict__ blkSW, const float* __restrict__ fccW,
                       const float* __restrict__ c1W, const float* __restrict__ c2W,
                       float* __restrict__ WposTp, float* __restrict__ bposP,
                       ushort* __restrict__ Wcat, ushort* __restrict__ W1p,
                       ushort* __restrict__ Wcp,
                       ushort* __restrict__ WB1, ushort* __restrict__ WB2,
                       int* __restrict__ hist){
    int t = blockIdx.x*256 + threadIdx.x;
    if (t < 384){ int d = t/128, s = t%128;
        int j = (s<64)? p64i(s) : 64 + p64i(s-64);
        WposTp[t] = fc_pos_W[j*3 + d]; return; }
    t -= 384;
    if (t < 128){ int j = (t<64)? p64i(t) : 64 + p64i(t-64);
        bposP[t] = fc_pos_b[j]; return; }
    t -= 128;
    if (t < 49152){ // Wcat[i][n 128][k' 128]: n<64 -> W0 row n, n>=64 -> Ws row n-64
        int i = t/16384, r = t%16384, n = r/128, kp = r%128;
        int ci = (kp<64)? p64i(kp) : 64 + p64i(kp-64);
        float v = (n<64)? blk0W[(i*64+n)*128 + ci] : blkSW[(i*64+(n-64))*128 + ci];
        Wcat[t] = f2bf(v); return; }
    t -= 49152;
    if (t < 12288){ // W1p[i][n 64][k' 64]
        int i = t/4096, r = t%4096, n = r/64, kp = r%64;
        W1p[t] = f2bf(blk1W[(i*64+n)*64 + p64i(kp)]); return; }
    t -= 12288;
    if (t < 16384){ // Wcp[n 256][k' 64]
        int n = t/64, kp = t%64;
        Wcp[t] = f2bf(fccW[n*64 + p64i(kp)]); return; }
    t -= 16384;
    if (t < 589824){ // WB1t [tap][cc][kc][q][ko 256][8e] -- coalesced conv b-loads; k' in G slot order
        int e = t & 7; int rest = t >> 3; int ko = rest & 255; int g5 = rest >> 8;
        int qq = g5 & 3; int kc = (g5 >> 2) & 1; int cc = (g5 >> 3) & 3; int tap = g5 >> 5;
        int kp = cc*64 + kc*32 + qq*8 + e;
        int ci = 64*(kp>>6) + p64i(kp & 63);
        WB1[t] = f2bf(c1W[(ko*256+ci)*9 + tap]); return; }
    t -= 589824;
    if (t < 589824){ // WB2t same layout, natural channels
        int e = t & 7; int rest = t >> 3; int ko = rest & 255; int g5 = rest >> 8;
        int qq = g5 & 3; int kc = (g5 >> 2) & 1; int cc = (g5 >> 3) & 3; int tap = g5 >> 5;
        int kp = cc*64 + kc*32 + qq*8 + e;
        WB2[t] = f2bf(c2W[(ko*256+kp)*9 + tap]); return; }
    t -= 589824;
    if (t < NSORT*R2){ hist[t] = 0; return; }   // replaces hipMemsetAsync
}

// ---- fc_pos + plane/query bins + hist atomics. NET0 bf16 [B][PSTR][128] slot order ----
__global__ void k_net0(const float* __restrict__ p, const float* __restrict__ query,
                       const float* __restrict__ WposTp, const float* __restrict__ bposP,
                       ushort* __restrict__ NET0, int* __restrict__ IDX,
                       int* __restrict__ hist){
    int pt = blockIdx.x*256 + threadIdx.x;
    int b = blockIdx.y;
    if (pt >= NPTS) return;
    const float* pp = p + ((long)b*NPTS + pt)*3;
    float p0 = pp[0], p1 = pp[1], p2 = pp[2];
    int c0 = coord_bin(p0), c1 = coord_bin(p1), c2 = coord_bin(p2);
    int i0 = c0 + 64*c2, i1 = c0 + 64*c1, i2 = c1 + 64*c2;
    IDX[(0*BB + b)*NPTS + pt] = i0;   // xz
    IDX[(1*BB + b)*NPTS + pt] = i1;   // xy
    IDX[(2*BB + b)*NPTS + pt] = i2;   // yz
    atomicAdd(&hist[(0*BB + b)*R2 + i0], 1);
    atomicAdd(&hist[(1*BB + b)*R2 + i1], 1);
    atomicAdd(&hist[(2*BB + b)*R2 + i2], 1);
    // query 3D coarse bin as sort-image 12+b
    const float* qp = query + ((long)b*NPTS + pt)*3;
    int qx = min((int)(fmaxf(qp[0], 0.0f)*16.0f), 15);
    int qy = min((int)(fmaxf(qp[1], 0.0f)*16.0f), 15);
    int qz = min((int)(fmaxf(qp[2], 0.0f)*16.0f), 15);
    int qi = (qx<<8) | (qy<<4) | qz;
    IDX[(12 + b)*NPTS + pt] = qi;
    atomicAdd(&hist[(12 + b)*R2 + qi], 1);
    ushort* out = NET0 + ((long)b*PSTR + pt)*128;
    #pragma unroll
    for (int s = 0; s < 128; s += 4){
        ushort4 v;
        v.x = f2bf(bposP[s+0] + p0*WposTp[s+0] + p1*WposTp[128+s+0] + p2*WposTp[256+s+0]);
        v.y = f2bf(bposP[s+1] + p0*WposTp[s+1] + p1*WposTp[128+s+1] + p2*WposTp[256+s+1]);
        v.z = f2bf(bposP[s+2] + p0*WposTp[s+2] + p1*WposTp[128+s+2] + p2*WposTp[256+s+2]);
        v.w = f2bf(bposP[s+3] + p0*WposTp[s+3] + p1*WposTp[128+s+3] + p2*WposTp[256+s+3]);
        *(ushort4*)(out + s) = v;
    }
}

__global__ void k_scan(const int* __restrict__ hist, int* __restrict__ binStart,
                       int* __restrict__ cursor){
    __shared__ int sums[256];
    int img = blockIdx.x; int tid = threadIdx.x;
    int v[16]; int s = 0;
    const int* h = hist + img*R2 + tid*16;
    #pragma unroll
    for (int i=0;i<16;i++){ v[i] = s; s += h[i]; }
    sums[tid] = s;
    __syncthreads();
    for (int d=1; d<256; d<<=1){
        int t = (tid>=d)? sums[tid-d] : 0;
        __syncthreads();
        sums[tid] += t;
        __syncthreads();
    }
    int base = (tid==0)? 0 : sums[tid-1];
    int* bs = binStart + img*R2 + tid*16;
    int* cu = cursor  + img*R2 + tid*16;
    #pragma unroll
    for (int i=0;i<16;i++){ bs[i] = base + v[i]; cu[i] = base + v[i]; }
}

__global__ void k_mklist(const int* __restrict__ IDX, int* __restrict__ cursor,
                         int* __restrict__ plist, int n){
    int t = blockIdx.x*256 + threadIdx.x;
    if (t >= n) return;
    int img = t / NPTS; int pt = t - img*NPTS;
    int bin = IDX[t];
    int pos = atomicAdd(&cursor[img*R2 + bin], 1);
    plist[img*NPTS + pos] = pt;
}

// ---- resblock on MFMA: wave=64 pts. GEMM1 [64x128]@[128->h64|sc64], LDS transpose,
//      GEMM2 relu(h)@W1 [64x64]; Y = sc + relu(dx), bf16 slot order.
//      POOLED: X2 half gathered from compact bin-mean table via idx_xz (L2-resident) ----
template<bool POOLED>
__global__ void __launch_bounds__(256) k_res_mfma(
        const ushort* __restrict__ X1, const ushort* __restrict__ X2, int s1, int s2,
        const int* __restrict__ idxp,
        const ushort* __restrict__ Wcat, const float* __restrict__ b0,
        const ushort* __restrict__ W1p, const float* __restrict__ b1,
        ushort* __restrict__ Y){
    __shared__ __align__(16) ushort lds[4][64*72];
    int tid = threadIdx.x, lane = tid & 63, w = tid >> 6;
    int m16 = lane & 15, q = lane >> 4;
    int b = blockIdx.y;
    int pt0 = blockIdx.x*256 + w*64;
    const ushort* x1 = X1 + (long)b*PSTR*s1;
    const ushort* x2 = POOLED ? (X2 + (long)b*R2*64) : (X2 + (long)b*PSTR*s2);
    int bi[4];
    if (POOLED){
        const int* ip = idxp + (long)b*NPTS;   // xz plane bins; padded pts read in-bounds garbage
        #pragma unroll
        for (int mt=0; mt<4; mt++) bi[mt] = ip[pt0 + mt*16 + m16];
    }
    floatx4 accH[4][4], accS[4][4];
    #pragma unroll
    for (int nt=0; nt<4; nt++){
        float bv = b0[nt*16 + m16];
        #pragma unroll
        for (int mt=0; mt<4; mt++){
            floatx4 t = {bv,bv,bv,bv}; accH[mt][nt] = t;
            floatx4 z = {0.f,0.f,0.f,0.f}; accS[mt][nt] = z;
        }
    }
    #pragma unroll
    for (int kk=0; kk<4; kk++){
        int off = (kk&1)*32 + q*8;
        short8 a[4], bh[4], bs[4];
        #pragma unroll
        for (int mt=0; mt<4; mt++){
            const ushort* ap;
            if (kk < 2)       ap = x1 + (long)(pt0 + mt*16 + m16)*s1 + off;
            else if (POOLED)  ap = x2 + (long)bi[mt]*64 + off;
            else              ap = x2 + (long)(pt0 + mt*16 + m16)*s2 + off;
            a[mt] = *(const short8*)ap;
        }
        #pragma unroll
        for (int nt=0; nt<4; nt++){
            bh[nt] = *(const short8*)(Wcat + (nt*16 + m16)*128 + kk*32 + q*8);
            bs[nt] = *(const short8*)(Wcat + ((nt+4)*16 + m16)*128 + kk*32 + q*8);
        }
        #pragma unroll
        for (int mt=0; mt<4; mt++)
            #pragma unroll
            for (int nt=0; nt<4; nt++){
                accH[mt][nt] = __builtin_amdgcn_mfma_f32_16x16x32_bf16(a[mt], bh[nt], accH[mt][nt], 0,0,0);
                accS[mt][nt] = __builtin_amdgcn_mfma_f32_16x16x32_bf16(a[mt], bs[nt], accS[mt][nt], 0,0,0);
            }
    }
    // relu(h) -> LDS in slot order (slot = m16*4 + nt, packed ushort4)
    ushort* myl = lds[w];
    #pragma unroll
    for (int mt=0; mt<4; mt++)
        #pragma unroll
        for (int r=0; r<4; r++){
            int ptl = mt*16 + q*4 + r;
            ushort4 hv;
            hv.x = f2bf(fmaxf(accH[mt][0][r], 0.0f));
            hv.y = f2bf(fmaxf(accH[mt][1][r], 0.0f));
            hv.z = f2bf(fmaxf(accH[mt][2][r], 0.0f));
            hv.w = f2bf(fmaxf(accH[mt][3][r], 0.0f));
            *(ushort4*)&myl[ptl*72 + m16*4] = hv;
        }
    // GEMM2: dx = relu(h) @ W1^T
    floatx4 accD[4][4];
    #pragma unroll
    for (int nt=0; nt<4; nt++){
        float bv = b1[nt*16 + m16];
        #pragma unroll
        for (int mt=0; mt<4; mt++){ floatx4 t = {bv,bv,bv,bv}; accD[mt][nt] = t; }
    }
    #pragma unroll
    for (int kk=0; kk<2; kk++){
        short8 a[4], bb[4];
        #pragma unroll
        for (int mt=0; mt<4; mt++)
            a[mt] = *(const short8*)&myl[(mt*16 + m16)*72 + kk*32 + q*8];
        #pragma unroll
        for (int nt=0; nt<4; nt++)
            bb[nt] = *(const short8*)(W1p + (nt*16 + m16)*64 + kk*32 + q*8);
        #pragma unroll
        for (int mt=0; mt<4; mt++)
            #pragma unroll
            for (int nt=0; nt<4; nt++)
                accD[mt][nt] = __builtin_amdgcn_mfma_f32_16x16x32_bf16(a[mt], bb[nt], accD[mt][nt], 0,0,0);
    }
    // Y = sc + relu(dx), slot-packed stores
    #pragma unroll
    for (int mt=0; mt<4; mt++)
        #pragma unroll
        for (int r=0; r<4; r++){
            int pt = pt0 + mt*16 + q*4 + r;
            if (pt < NPTS){
                ushort4 yv;
                yv.x = f2bf(accS[mt][0][r] + fmaxf(accD[mt][0][r], 0.0f));
                yv.y = f2bf(accS[mt][1][r] + fmaxf(accD[mt][1][r], 0.0f));
                yv.z = f2bf(accS[mt][2][r] + fmaxf(accD[mt][2][r], 0.0f));
                yv.w = f2bf(accS[mt][3][r] + fmaxf(accD[mt][3][r], 0.0f));
                *(ushort4*)(Y + ((long)b*PSTR + pt)*64 + m16*4) = yv;
            }
        }
}

// ---- xz pooling: bin means into compact table BINP[b][bin][64] (2 MB, L2-resident) ----
__global__ void k_binmean(const ushort* __restrict__ Y, const int* __restrict__ plist,
                          const int* __restrict__ binStart, const int* __restrict__ hist,
                          ushort* __restrict__ BINP){
    int tid = threadIdx.x; int lane = tid & 63; int wv = tid >> 6;
    int g = blockIdx.x*4 + wv;          // [0, 4*4096)
    int b = g >> 12; int bl = g & 4095;
    int idx = b*R2 + bl;
    int start = binStart[idx]; int cnt = hist[idx];
    const int* pl = plist + b*NPTS;
    const ushort* Yb = Y + (long)b*PSTR*64 + lane;
    float s = bin_gather_sum(Yb, pl, start, cnt);
    BINP[(long)idx*64 + lane] = f2bf(s / fmaxf((float)cnt, 1.0f));
}

// ---- plane bin-means of net (64ch): mean commutes with the fc_c linear map ----
// wave per (img,bin); lane = slot; 4-unrolled gather (4 chains in flight)
__global__ void k_gather64(const ushort* __restrict__ Y, const int* __restrict__ plist,
                           const int* __restrict__ binStart, const int* __restrict__ hist,
                           ushort* __restrict__ BIN){
    int tid = threadIdx.x; int lane = tid & 63; int wv = tid >> 6;
    int g = blockIdx.x*4 + wv;          // [0, 12*4096)
    int img = g >> 12; int bl = g & 4095;
    int b = img & 3;
    int idx = img*R2 + bl;
    int start = binStart[idx]; int cnt = hist[idx];
    const int* pl = plist + img*NPTS;
    const ushort* Yb = Y + (long)b*PSTR*64 + lane;
    float s = bin_gather_sum(Yb, pl, start, cnt);
    BIN[(long)g*64 + lane] = f2bf(s / fmaxf((float)cnt, 1.0f));
}

// ---- fc_c applied to bin means: [49152 x 64] @ [64 -> 256] + bias, empty bins -> 0.
//      Output G keeps the established C/G slot order (n0 + m16*4 + nt). ----
__global__ void __launch_bounds__(256) k_fc_bins(const ushort* __restrict__ BIN,
        const ushort* __restrict__ Wcp, const float* __restrict__ bc,
        const int* __restrict__ hist, ushort* __restrict__ G){
    int tid = threadIdx.x, lane = tid & 63, w = tid >> 6;
    int m16 = lane & 15, q = lane >> 4;
    int r0 = blockIdx.x*64;             // bin row base (row = img*4096 + bl)
    int n0 = w*64;
    floatx4 acc[4][4];
    #pragma unroll
    for (int nt=0; nt<4; nt++){
        float bv = bc[n0 + nt*16 + m16];
        #pragma unroll
        for (int mt=0; mt<4; mt++){ floatx4 t = {bv,bv,bv,bv}; acc[mt][nt] = t; }
    }
    #pragma unroll
    for (int kk=0; kk<2; kk++){
        short8 a[4], bb[4];
        #pragma unroll
        for (int mt=0; mt<4; mt++)
            a[mt] = *(const short8*)(BIN + (long)(r0 + mt*16 + m16)*64 + kk*32 + q*8);
        #pragma unroll
        for (int nt=0; nt<4; nt++)
            bb[nt] = *(const short8*)(Wcp + (n0 + nt*16 + m16)*64 + kk*32 + q*8);
        #pragma unroll
        for (int mt=0; mt<4; mt++)
            #pragma unroll
            for (int nt=0; nt<4; nt++)
                acc[mt][nt] = __builtin_amdgcn_mfma_f32_16x16x32_bf16(a[mt], bb[nt], acc[mt][nt], 0,0,0);
    }
    #pragma unroll
    for (int mt=0; mt<4; mt++)
        #pragma unroll
        for (int r=0; r<4; r++){
            int row = r0 + mt*16 + q*4 + r;
            int cnt = hist[row];
            ushort4 v;
            if (cnt > 0){
                v.x = f2bf(acc[mt][0][r]); v.y = f2bf(acc[mt][1][r]);
                v.z = f2bf(acc[mt][2][r]); v.w = f2bf(acc[mt][3][r]);
            } else {
                v.x = 0; v.y = 0; v.z = 0; v.w = 0;   // ref: empty bin -> 0, not bias
            }
            *(ushort4*)(G + (long)row*256 + n0 + m16*4) = v;
        }
}

// ---- conv 3x3 SAME + relu, 9-tap implicit GEMM on MFMA (r6 GOLDEN — do not touch) ----
// 1 output row x 256 out-ch per block; LDS 49.5KB -> exactly 3 blocks/CU, grid 768
// co-resident (r5 lesson: co-residency beats per-block B-traffic halving; the
// 4-row x 64-ko variant was abandoned after r7 swizzle bug + r8 replay race).
// A: LDS dbuf per 64-ch chunk via global_load_lds; 16B slots XOR-swizzled by (colh&7)
//    with inverse swizzle on the global source; halo cols 0/65 pre-zeroed.
// B: WBt[tap][cc][kc][q][ko][8] -> contiguous coalesced loads.
__global__ void __launch_bounds__(256, 3) k_conv_mfma(const ushort* __restrict__ IN,
        const ushort* __restrict__ WBt, const float* __restrict__ bias, ushort* __restrict__ OUT){
    __shared__ __align__(16) ushort lds[2][3*66*64];
    int tid = threadIdx.x;
    int lane = tid & 63;
    int w = tid >> 6;
    int n0 = __builtin_amdgcn_readfirstlane(w * 64);
    // bijective XCD-aware swizzle: 768 workgroups = 8 XCDs x 96 consecutive
    int bid = blockIdx.x;
    int wg = (bid & 7) * 96 + (bid >> 3);
    int img = wg >> 6;
    int y = wg & 63;
    const ushort* inb = IN + (long)img*4096*256;
    int m16 = lane & 15, q = lane >> 4;

    // zero halo cells (colh 0 and 65) in both buffers, once: 12 cells x 8 slots
    if (tid < 96){
        int st = tid & 7; int c = tid >> 3;
        int buf = c / 6; int rr = (c % 6) >> 1; int colh = (c & 1) * 65;
        short8 z = {0,0,0,0,0,0,0,0};
        *(short8*)&lds[buf][(rr*66 + colh)*64 + st*8] = z;
    }

    floatx4 acc[4][4];
    #pragma unroll
    for (int j=0;j<4;j++){
        float bv = bias[n0 + 16*j + m16];
        #pragma unroll
        for (int i=0;i<4;i++){ floatx4 t = {bv,bv,bv,bv}; acc[i][j] = t; }
    }

    // staging lane constants: cell-in-group, slot, swizzled source channel-group
    int sgx = lane >> 3;                 // 0..7 cells per wave-load
    int sst = lane & 7;                  // LDS slot this lane fills
    int sg  = sst ^ ((1 + sgx) & 7);     // global channel-group to fetch (inverse swizzle)

    auto stage = [&](int buf, int cc){
        #pragma unroll
        for (int r3 = 0; r3 < 3; ++r3){
            int gy = y + r3 - 1;
            if (gy < 0 || gy > 63) continue;           // block-uniform
            const ushort* grow = inb + (long)gy*64*256 + cc*64 + sg*8;
            #pragma unroll
            for (int t = 0; t < 2; ++t){
                int col8 = w + t*4;
                const ushort* gp = grow + (long)(col8*8 + sgx)*256;
                ushort* lp = &lds[buf][(r3*66 + 1 + col8*8)*64];
                gl_lds16(gp, lp);
            }
        }
    };

    auto compute = [&](int buf, int cc){
        const ushort* lb = &lds[buf][0];
        #pragma unroll
        for (int r3 = 0; r3 < 3; ++r3){
            int gy = y + r3 - 1;
            if (gy < 0 || gy > 63) continue;           // block-uniform
            #pragma unroll
            for (int s = 0; s < 3; ++s){
                int tap = r3*3 + s;
                #pragma unroll
                for (int kc = 0; kc < 2; ++kc){
                    short8 a[4], b[4];
                    #pragma unroll
                    for (int j=0;j<4;j++)
                        b[j] = *(const short8*)(WBt + (long)(tap*32 + cc*8 + kc*4 + q)*2048
                                                    + (n0 + 16*j + m16)*8);
                    #pragma unroll
                    for (int i=0;i<4;i++){
                        int colh = 16*i + m16 + s;
                        int sl = (kc*4 + q) ^ (colh & 7);
                        a[i] = *(const short8*)(lb + (r3*66 + colh)*64 + sl*8);
                    }
                    #pragma unroll
                    for (int i=0;i<4;i++)
                        #pragma unroll
                        for (int j=0;j<4;j++)
                            acc[i][j] = __builtin_amdgcn_mfma_f32_16x16x32_bf16(a[i], b[j], acc[i][j], 0, 0, 0);
                }
            }
        }
    };

    stage(0, 0);
    __syncthreads();           // halo zeros + chunk 0 staged
    #pragma unroll 1
    for (int cc = 0; cc < 4; ++cc){
        if (cc < 3) stage((cc+1)&1, cc+1);   // async prefetch; hides under b-load waits
        compute(cc&1, cc);
        __syncthreads();                      // next chunk staged + buf free to overwrite
    }

    long base = ((long)img*4096 + (long)y*64);
    #pragma unroll
    for (int i=0;i<4;i++){
        #pragma unroll
        for (int rr=0;rr<4;rr++){
            int px = 16*i + q*4 + rr;
            long rowoff = (base + px)*256;
            #pragma unroll
            for (int j=0;j<4;j++){
                float v = fmaxf(acc[i][j][rr], 0.0f);
                OUT[rowoff + n0 + 16*j + m16] = f2bf(v);
            }
        }
    }
}

// ---- bilinear sample (border, align_corners=False), sum 3 planes; sorted queries ----
__global__ void k_sample(const ushort* __restrict__ A2, const float* __restrict__ query,
                         const int* __restrict__ qlist, float* __restrict__ out){
    int lane = threadIdx.x & 63;
    int g = blockIdx.x*4 + (threadIdx.x >> 6);
    int b = blockIdx.y;
    int q = qlist[b*NPTS + g];
    const float* qp = query + ((long)b*NPTS + q)*3;
    float q0 = qp[0], q1 = qp[1], q2 = qp[2];
    float a0 = 0.f, a1 = 0.f, a2v = 0.f, a3 = 0.f;
    #pragma unroll
    for (int pl = 0; pl < 3; pl++){
        float qa = (pl==2) ? q1 : q0;
        float qb = (pl==1) ? q1 : q2;
        float gx = qa*2.0f - 1.0f, gy = qb*2.0f - 1.0f;
        float xf = ((gx + 1.0f)*64.0f - 1.0f)*0.5f;
        float yf = ((gy + 1.0f)*64.0f - 1.0f)*0.5f;
        xf = fminf(fmaxf(xf, 0.0f), 63.0f);
        yf = fminf(fmaxf(yf, 0.0f), 63.0f);
        float x0f = floorf(xf), y0f = floorf(yf);
        float wx = xf - x0f, wy = yf - y0f;
        int x0 = (int)x0f, y0 = (int)y0f;
        int x1 = min(x0+1, 63), y1 = min(y0+1, 63);
        const ushort* base = A2 + ((long)(pl*BB+b)*R2)*256 + lane*4;
        ushort4 t00 = *(const ushort4*)(base + (long)(y0*64+x0)*256);
        ushort4 t01 = *(const ushort4*)(base + (long)(y0*64+x1)*256);
        ushort4 t10 = *(const ushort4*)(base + (long)(y1*64+x0)*256);
        ushort4 t11 = *(const ushort4*)(base + (long)(y1*64+x1)*256);
        float w00 = (1.0f-wx)*(1.0f-wy), w01 = wx*(1.0f-wy);
        float w10 = (1.0f-wx)*wy,        w11 = wx*wy;
        a0  += bf2f(t00.x)*w00 + bf2f(t01.x)*w01 + bf2f(t10.x)*w10 + bf2f(t11.x)*w11;
        a1  += bf2f(t00.y)*w00 + bf2f(t01.y)*w01 + bf2f(t10.y)*w10 + bf2f(t11.y)*w11;
        a2v += bf2f(t00.z)*w00 + bf2f(t01.z)*w01 + bf2f(t10.z)*w10 + bf2f(t11.z)*w11;
        a3  += bf2f(t00.w)*w00 + bf2f(t01.w)*w01 + bf2f(t10.w)*w10 + bf2f(t11.w)*w11;
    }
    float4 r; r.x = a0; r.y = a1; r.z = a2v; r.w = a3;
    *(float4*)(out + ((long)b*NPTS + q)*256 + lane*4) = r;
}

extern "C" void kernel_launch(void* const* d_in, const int* in_sizes, int n_in,
                              void* d_out, int out_size, void* d_ws, size_t ws_size,
                              hipStream_t stream){
    (void)in_sizes; (void)n_in; (void)out_size; (void)ws_size;
    const float* p        = (const float*)d_in[0];
    const float* query    = (const float*)d_in[1];
    const float* fc_pos_W = (const float*)d_in[2];
    const float* fc_pos_b = (const float*)d_in[3];
    const float* blk0W    = (const float*)d_in[4];
    const float* blk0b    = (const float*)d_in[5];
    const float* blk1W    = (const float*)d_in[6];
    const float* blk1b    = (const float*)d_in[7];
    const float* blkSW    = (const float*)d_in[8];
    const float* fccW     = (const float*)d_in[9];
    const float* fccB     = (const float*)d_in[10];
    const float* c1W      = (const float*)d_in[11];
    const float* c1b      = (const float*)d_in[12];
    const float* c2W      = (const float*)d_in[13];
    const float* c2b      = (const float*)d_in[14];

    char* ws = (char*)d_ws;
    size_t off = 0;
    auto alloc = [&](size_t bytes)->char*{
        char* r = ws + off; off = (off + bytes + 255) & ~(size_t)255; return r; };
    float* WposTp = (float*)alloc(384*4);
    float* bposP  = (float*)alloc(128*4);
    ushort* Wcat  = (ushort*)alloc(49152UL*2);
    ushort* W1p   = (ushort*)alloc(12288UL*2);
    ushort* Wcp   = (ushort*)alloc(16384UL*2);
    ushort* WB1   = (ushort*)alloc(589824UL*2);
    ushort* WB2   = (ushort*)alloc(589824UL*2);
    int*   IDX   = (int*)  alloc((size_t)NSORT*NPTS*4);   // 12 plane imgs + 4 query imgs
    int*   hist  = (int*)  alloc((size_t)NSORT*R2*4);
    int*   binStart = (int*)alloc((size_t)NSORT*R2*4);
    int*   cursor   = (int*)alloc((size_t)NSORT*R2*4);
    int*   plist    = (int*)alloc((size_t)NSORT*NPTS*4);
    ushort* NET0 = (ushort*)alloc((size_t)BB*PSTR*128*2);
    ushort* Ya   = (ushort*)alloc((size_t)BB*PSTR*64*2);
    ushort* Yb   = (ushort*)alloc((size_t)BB*PSTR*64*2);
    ushort* BINP = (ushort*)alloc((size_t)BB*R2*64*2);    // compact xz pooling table (2 MB)
    ushort* BIN64= (ushort*)alloc((size_t)NIMG*R2*64*2);
    ushort* G    = (ushort*)alloc(12582912UL*2);
    ushort* A1   = (ushort*)alloc(12582912UL*2);
    ushort* A2   = (ushort*)alloc(12582912UL*2);

    dim3 blk(256);
    // k_prep also zeroes hist (range appended past the weight ranges)
    k_prep<<<5170, blk, 0, stream>>>(fc_pos_W, fc_pos_b, blk0W, blk1W, blkSW, fccW, c1W, c2W,
                                     WposTp, bposP, Wcat, W1p, Wcp, WB1, WB2, hist);
    // net0 computes IDX + hist atomics (k_hist fused)
    k_net0<<<dim3(118, BB), blk, 0, stream>>>(p, query, WposTp, bposP, NET0, IDX, hist);
    k_scan  <<<NSORT, blk, 0, stream>>>(hist, binStart, cursor);
    k_mklist<<<(NSORT*NPTS + 255)/256, blk, 0, stream>>>(IDX, cursor, plist, NSORT*NPTS);
    // resblock 0: X1 = NET0 slots [0,64), X2 = NET0 slots [64,128)
    k_res_mfma<false><<<dim3(118,BB), blk, 0, stream>>>(NET0, NET0 + 64, 128, 128, nullptr,
                                                 Wcat, blk0b, W1p, blk1b, Ya);
    k_binmean<<<4096, blk, 0, stream>>>(Ya, plist, binStart, hist, BINP);
    k_res_mfma<true><<<dim3(118,BB), blk, 0, stream>>>(Ya, BINP, 64, 64, IDX,
                                                 Wcat + 16384, blk0b + 64, W1p + 4096, blk1b + 64, Yb);
    k_binmean<<<4096, blk, 0, stream>>>(Yb, plist, binStart, hist, BINP);
    k_res_mfma<true><<<dim3(118,BB), blk, 0, stream>>>(Yb, BINP, 64, 64, IDX,
                                                 Wcat + 32768, blk0b + 128, W1p + 8192, blk1b + 128, Ya);
    // mean-then-GEMM fusion: bin-means of net (64ch, one wave/bin, 4-unrolled gather),
    // then fc_c on 49152 bins -> G  (r9 lesson: keep gather at max wave-parallelism)
    k_gather64<<<12288, blk, 0, stream>>>(Ya, plist, binStart, hist, BIN64);
    k_fc_bins<<<768, blk, 0, stream>>>(BIN64, Wcp, fccB, hist, G);
    // convs on MFMA: r6 golden structure (1 row x 256 ch, 3 blocks/CU co-resident)
    k_conv_mfma<<<dim3(768), blk, 0, stream>>>(G,  WB1, c1b, A1);
    k_conv_mfma<<<dim3(768), blk, 0, stream>>>(A1, WB2, c2b, A2);
    // bilinear sample + plane sum, spatially-sorted query order (query sort = imgs 12..15)
    k_sample<<<dim3(7500,BB), blk, 0, stream>>>(A2, query, plist + 12*NPTS, (float*)d_out);
}